// Round 6
// baseline (103.238 us; speedup 1.0000x reference)
//
#include <hip/hip_runtime.h>
#include <hip/hip_fp16.h>
#include <math.h>

#define BATCH     128
#define N_NODES   32768
#define N_CHILD   65536
#define NNZ_TOTAL 1048576

// ---------------------------------------------------------------------------
// Kernel 1: ex[c][b] = (half)exp(child_ll[b][c])  (tiled transpose via LDS)
// Each 256B table row spans 4 cache lines; batch-quarter q == line q.
// ---------------------------------------------------------------------------
__global__ __launch_bounds__(256) void exp_transpose_kernel(
    const float* __restrict__ child_ll, __half* __restrict__ ex) {
    __shared__ float tile[64][BATCH + 1];
    const int c0 = blockIdx.x * 64;
    const int t  = threadIdx.x;

    {
        const int cl = t & 63;
        const int b0 = t >> 6;  // 0..3
#pragma unroll
        for (int j = 0; j < BATCH / 4; ++j) {
            const int b = b0 + j * 4;
            tile[cl][b] = expf(child_ll[(size_t)b * N_CHILD + c0 + cl]);
        }
    }
    __syncthreads();

    {
        const int cl = t >> 4;         // 0..15
        const int b0 = (t & 15) * 8;   // 0..120
#pragma unroll
        for (int p = 0; p < 4; ++p) {
            const int c = p * 16 + cl;
            union { __half2 h[4]; uint4 u; } pk;
#pragma unroll
            for (int k = 0; k < 4; ++k)
                pk.h[k] = __half2{__float2half(tile[c][b0 + 2 * k]),
                                  __float2half(tile[c][b0 + 2 * k + 1])};
            *(uint4*)&ex[(size_t)(c0 + c) * BATCH + b0] = pk.u;
        }
    }
}

// ---------------------------------------------------------------------------
// Kernel 2: w[i] = exp(log_w[i])
// ---------------------------------------------------------------------------
__global__ __launch_bounds__(256) void exp_w_kernel(
    const float* __restrict__ log_w, float* __restrict__ w) {
    const int i = (blockIdx.x * 256 + threadIdx.x) * 4;
    float4 v = *(const float4*)&log_w[i];
    v.x = expf(v.x); v.y = expf(v.y); v.z = expf(v.z); v.w = expf(v.w);
    *(float4*)&w[i] = v;
}

// ---------------------------------------------------------------------------
// Kernel 3: row_start[r] = lower_bound(rows, r); rows is sorted.
// ---------------------------------------------------------------------------
__global__ __launch_bounds__(256) void row_starts_kernel(
    const int* __restrict__ rows, int* __restrict__ row_start) {
    const int r = blockIdx.x * blockDim.x + threadIdx.x;
    if (r > N_NODES) return;
    if (r == N_NODES) { row_start[r] = NNZ_TOTAL; return; }
    int lo = 0, hi = NNZ_TOTAL;
    while (lo < hi) {
        const int mid = (lo + hi) >> 1;
        if (rows[mid] < r) lo = mid + 1; else hi = mid;
    }
    row_start[r] = lo;
}

// ---------------------------------------------------------------------------
// Kernel 4: batch-quartered per-row sum. quarter = (bid&7)>>1 pins each
// XCD (bid%8 round-robin) to ONE 4.0-MiB line-slice of the table -> the
// gather working set fits that XCD's L2 exactly. 4 lanes/row x 16B = one
// dwordx4 covers 16 nnz; up to 4 gathers in flight per wave.
// ---------------------------------------------------------------------------
__global__ __launch_bounds__(256, 4) void sum_rows_kernel(
    const __half* __restrict__ ex, const float* __restrict__ w,
    const int* __restrict__ cols, const int* __restrict__ row_start,
    float* __restrict__ out) {
    const int wave = threadIdx.x >> 6;     // 0..3 (row within block)
    const int lane = threadIdx.x & 63;
    const int bid  = blockIdx.x;           // grid = 32768
    const int xcd  = bid & 7;              // bid%8 round-robins XCDs
    const int quarter = xcd >> 1;          // 0..3 : one table line-slice
    const int parity  = xcd & 1;
    const int rowblk  = (bid >> 3) * 2 + parity;   // 0..8191
    const int r       = rowblk * 4 + wave;         // 0..32767

    const int start = row_start[r];
    const int end   = row_start[r + 1];
    const char* exb = (const char*)ex;
    const int  gslot = lane >> 2;                  // nnz slot in granule 0..15
    const unsigned sub = (unsigned)lane & 3u;      // 16B chunk within 64B line
    const unsigned qoff = (unsigned)quarter * 64u + sub * 16u;

    float acc[8] = {0.f, 0.f, 0.f, 0.f, 0.f, 0.f, 0.f, 0.f};
    float wlane = 0.f;

    for (int base = start; base < end; base += 64) {
        const int  idx   = base + lane;
        const bool valid = idx < end;
        const int   c  = __builtin_nontemporal_load(&cols[valid ? idx : start]);
        const float wv = valid ? __builtin_nontemporal_load(&w[idx]) : 0.f;
        wlane += wv;
        const int seg = end - base;                // wave-uniform

        int   ct[4];
        float wt[4];
        uint4 g[4];

        // Phase A: redistribute cols+weights to 16-nnz granule layout
#pragma unroll
        for (int t = 0; t < 4; ++t) {
            if (t * 16 < seg) {
                const int pa = (t * 16 + gslot) * 4;
                ct[t] = __builtin_amdgcn_ds_bpermute(pa, c);
                wt[t] = __uint_as_float(__builtin_amdgcn_ds_bpermute(
                    pa, __float_as_uint(wv)));
            }
        }
        // Phase B: issue all gathers (16 nnz per dwordx4, 4 in flight)
#pragma unroll
        for (int t = 0; t < 4; ++t) {
            if (t * 16 < seg)
                g[t] = *(const uint4*)(exb + ((size_t)(unsigned)ct[t] << 8) + qoff);
        }
        // Phase C: consume
#pragma unroll
        for (int t = 0; t < 4; ++t) {
            if (t * 16 < seg) {
                const __half2* hp = (const __half2*)&g[t];
#pragma unroll
                for (int k = 0; k < 4; ++k) {
                    const float2 f = __half22float2(hp[k]);
                    acc[2 * k]     = fmaf(wt[t], f.x, acc[2 * k]);
                    acc[2 * k + 1] = fmaf(wt[t], f.y, acc[2 * k + 1]);
                }
            }
        }
    }

    // fold the 16 row-groups (same batch samples) together
#pragma unroll
    for (int k = 0; k < 8; ++k) {
        acc[k] += __shfl_xor(acc[k], 4, 64);
        acc[k] += __shfl_xor(acc[k], 8, 64);
        acc[k] += __shfl_xor(acc[k], 16, 64);
        acc[k] += __shfl_xor(acc[k], 32, 64);
    }
    // wave-parallel normalization sum
    float wsum = wlane;
#pragma unroll
    for (int m = 1; m < 64; m <<= 1) wsum += __shfl_xor(wsum, m, 64);
    const float logz = logf(wsum);

    if (lane < 4) {
        const int b0 = quarter * 32 + (int)sub * 8;
#pragma unroll
        for (int k = 0; k < 8; ++k)
            out[(size_t)(b0 + k) * N_NODES + r] = logf(acc[k]) - logz;
    }
}

// ---------------------------------------------------------------------------
extern "C" void kernel_launch(void* const* d_in, const int* in_sizes, int n_in,
                              void* d_out, int out_size, void* d_ws, size_t ws_size,
                              hipStream_t stream) {
    const float* child_ll = (const float*)d_in[0];
    const float* log_w    = (const float*)d_in[1];
    const int*   rows     = (const int*)d_in[2];
    const int*   cols     = (const int*)d_in[3];
    float*       out      = (float*)d_out;

    __half* ex        = (__half*)d_ws;                                        // 16.78 MB
    float*  w         = (float*)((char*)d_ws + (size_t)N_CHILD * BATCH * 2);  // 4 MB
    int*    row_start = (int*)((char*)w + (size_t)NNZ_TOTAL * 4);             // 128 KB

    exp_transpose_kernel<<<N_CHILD / 64, 256, 0, stream>>>(child_ll, ex);
    exp_w_kernel<<<NNZ_TOTAL / 1024, 256, 0, stream>>>(log_w, w);
    row_starts_kernel<<<(N_NODES + 256) / 256 + 1, 256, 0, stream>>>(rows, row_start);
    // grid = 8192 row-blocks x 4 quarters; quarter/parity derived from bid&7
    sum_rows_kernel<<<N_NODES / 4 * 4, 256, 0, stream>>>(ex, w, cols, row_start, out);
}

// Round 7
// 70.878 us; speedup vs baseline: 1.4566x; 1.4566x over previous
//
#include <hip/hip_runtime.h>
#include <math.h>

#define BATCH     128
#define N_NODES   32768
#define N_CHILD   65536
#define NNZ_TOTAL 1048576

typedef __attribute__((ext_vector_type(2))) float fx2;

// ---------------------------------------------------------------------------
// Kernel A: fp8 exp table with per-column power-of-2 scaling.
//   ex8[c][b] = e4m3( exp(child_ll[b][c]) * 2^k_c ),  colmax*2^k_c in [128,256)
//   winv[c]   = 2^-k_c   (folded into weights later; exact)
// Row = 128 B = 2 cache lines.
// ---------------------------------------------------------------------------
__global__ __launch_bounds__(256) void exp_transpose_fp8_kernel(
    const float* __restrict__ child_ll, unsigned char* __restrict__ ex8,
    float* __restrict__ winv) {
    __shared__ float tile[64][BATCH + 1];
    __shared__ float sc[64];
    const int c0 = blockIdx.x * 64;
    const int t  = threadIdx.x;

    {   // load + exp (coalesced in c)
        const int cl = t & 63;
        const int b0 = t >> 6;  // 0..3
#pragma unroll
        for (int j = 0; j < BATCH / 4; ++j) {
            const int b = b0 + j * 4;
            tile[cl][b] = expf(child_ll[(size_t)b * N_CHILD + c0 + cl]);
        }
    }
    __syncthreads();

    if (t < 64) {  // per-column max -> power-of-2 scale
        float m = tile[t][0];
#pragma unroll 4
        for (int b = 1; b < BATCH; ++b) m = fmaxf(m, tile[t][b]);
        const int k = 7 - ilogbf(m);        // colmax*2^k in [128,256) < 448
        sc[t] = ldexpf(1.f, k);
        winv[c0 + t] = ldexpf(1.f, -k);
    }
    __syncthreads();

    {   // pack + store: 8 threads/column, 16 B each (coalesced)
        const int sub = t & 7;
        const int b0  = sub * 16;
#pragma unroll
        for (int p = 0; p < 2; ++p) {
            const int c = (t >> 3) + p * 32;
            const float s = sc[c];
            uint4 o;
            unsigned* ow = (unsigned*)&o;
#pragma unroll
            for (int q = 0; q < 4; ++q) {
                unsigned v = 0;
                v = __builtin_amdgcn_cvt_pk_fp8_f32(
                        tile[c][b0 + q * 4 + 0] * s, tile[c][b0 + q * 4 + 1] * s, v, false);
                v = __builtin_amdgcn_cvt_pk_fp8_f32(
                        tile[c][b0 + q * 4 + 2] * s, tile[c][b0 + q * 4 + 3] * s, v, true);
                ow[q] = v;
            }
            *(uint4*)&ex8[(size_t)(c0 + c) * 128 + (unsigned)b0] = o;
        }
    }
}

// ---------------------------------------------------------------------------
// Kernel B (fused): blocks [0,1024): wfold[i] = exp(log_w[i]) * winv[cols[i]]
//                   blocks [1024,1153): row_start via binary search
// ---------------------------------------------------------------------------
__global__ __launch_bounds__(256) void prep_kernel(
    const float* __restrict__ log_w, const int* __restrict__ cols,
    const float* __restrict__ winv, const int* __restrict__ rows,
    float* __restrict__ wfold, int* __restrict__ row_start) {
    const int bid = blockIdx.x;
    const int t   = threadIdx.x;
    if (bid < 1024) {
        const int i = (bid * 256 + t) * 4;
        const float4 lw = *(const float4*)&log_w[i];
        const int4   cc = *(const int4*)&cols[i];
        float4 o;
        o.x = expf(lw.x) * winv[cc.x];
        o.y = expf(lw.y) * winv[cc.y];
        o.z = expf(lw.z) * winv[cc.z];
        o.w = expf(lw.w) * winv[cc.w];
        *(float4*)&wfold[i] = o;
    } else {
        const int r = (bid - 1024) * 256 + t;
        if (r > N_NODES) return;
        if (r == N_NODES) { row_start[r] = NNZ_TOTAL; return; }
        int lo = 0, hi = NNZ_TOTAL;
        while (lo < hi) {
            const int mid = (lo + hi) >> 1;
            if (rows[mid] < r) lo = mid + 1; else hi = mid;
        }
        row_start[r] = lo;
    }
}

// ---------------------------------------------------------------------------
// Kernel C: per-row sum, one wave per row. fp8 rows: 8 lanes x 16B per row
// => one dwordx4 instr covers 8 nnz (2 lines/nnz, half of fp16). 8 gathers
// (64 nnz) in flight; bpermute redistribution; true-w sum for log_z.
// ---------------------------------------------------------------------------
__global__ __launch_bounds__(256, 4) void sum_rows_kernel(
    const unsigned char* __restrict__ ex8, const float* __restrict__ wfold,
    const float* __restrict__ log_w, const int* __restrict__ cols,
    const int* __restrict__ row_start, float* __restrict__ out) {
    const int wave = threadIdx.x >> 6;   // 0..3
    const int lane = threadIdx.x & 63;
    const int bid  = blockIdx.x;         // grid = 8192
    const int rb   = (bid & 7) * (N_NODES / 4 / 8) + (bid >> 3);
    const int r    = rb * 4 + wave;

    const int start = row_start[r];
    const int end   = row_start[r + 1];
    const int  slot = lane >> 3;                   // nnz slot within granule
    const unsigned sub = (unsigned)lane & 7u;      // 16B chunk within 128B row
    const unsigned boff = sub * 16u;

    float acc[16];
#pragma unroll
    for (int k = 0; k < 16; ++k) acc[k] = 0.f;
    float wlane = 0.f;

    for (int base = start; base < end; base += 64) {
        const int  idx   = base + lane;
        const bool valid = idx < end;
        const int   c  = __builtin_nontemporal_load(&cols[valid ? idx : start]);
        const float wf = valid ? __builtin_nontemporal_load(&wfold[idx]) : 0.f;
        wlane += valid ? expf(__builtin_nontemporal_load(&log_w[idx])) : 0.f;
        const int seg = end - base;                // wave-uniform

        int   ct[8];
        float wt[8];
        uint4 g[8];

        // Phase A: redistribute cols+folded weights (8-nnz granules)
#pragma unroll
        for (int t8 = 0; t8 < 8; ++t8) {
            if (t8 * 8 < seg) {
                const int pa = (t8 * 8 + slot) * 4;
                ct[t8] = __builtin_amdgcn_ds_bpermute(pa, c);
                wt[t8] = __uint_as_float(__builtin_amdgcn_ds_bpermute(
                    pa, __float_as_uint(wf)));
            }
        }
        // Phase B: issue all gathers (8 dwordx4 in flight, 8 nnz each)
#pragma unroll
        for (int t8 = 0; t8 < 8; ++t8) {
            if (t8 * 8 < seg)
                g[t8] = *(const uint4*)(ex8 +
                        ((size_t)(unsigned)ct[t8] << 7) + boff);
        }
        // Phase C: consume (fp8 -> f32 via packed HW cvt)
#pragma unroll
        for (int t8 = 0; t8 < 8; ++t8) {
            if (t8 * 8 < seg) {
                const float wtv = wt[t8];
                const unsigned* gu = (const unsigned*)&g[t8];
#pragma unroll
                for (int q = 0; q < 4; ++q) {
                    const fx2 lo = __builtin_amdgcn_cvt_pk_f32_fp8((int)gu[q], false);
                    const fx2 hi = __builtin_amdgcn_cvt_pk_f32_fp8((int)gu[q], true);
                    acc[q * 4 + 0] = fmaf(wtv, lo.x, acc[q * 4 + 0]);
                    acc[q * 4 + 1] = fmaf(wtv, lo.y, acc[q * 4 + 1]);
                    acc[q * 4 + 2] = fmaf(wtv, hi.x, acc[q * 4 + 2]);
                    acc[q * 4 + 3] = fmaf(wtv, hi.y, acc[q * 4 + 3]);
                }
            }
        }
    }

    // fold the 8 slot-groups (same batch samples) together
#pragma unroll
    for (int k = 0; k < 16; ++k) {
        acc[k] += __shfl_xor(acc[k], 8, 64);
        acc[k] += __shfl_xor(acc[k], 16, 64);
        acc[k] += __shfl_xor(acc[k], 32, 64);
    }
    // wave-parallel true-weight sum for log_z
    float wsum = wlane;
#pragma unroll
    for (int m = 1; m < 64; m <<= 1) wsum += __shfl_xor(wsum, m, 64);
    const float logz = logf(wsum);

    if (lane < 8) {
        const int b0 = lane * 16;
#pragma unroll
        for (int k = 0; k < 16; ++k)
            out[(size_t)(b0 + k) * N_NODES + r] = logf(acc[k]) - logz;
    }
}

// ---------------------------------------------------------------------------
extern "C" void kernel_launch(void* const* d_in, const int* in_sizes, int n_in,
                              void* d_out, int out_size, void* d_ws, size_t ws_size,
                              hipStream_t stream) {
    const float* child_ll = (const float*)d_in[0];
    const float* log_w    = (const float*)d_in[1];
    const int*   rows     = (const int*)d_in[2];
    const int*   cols     = (const int*)d_in[3];
    float*       out      = (float*)d_out;

    // workspace layout
    unsigned char* ex8    = (unsigned char*)d_ws;                          // 8.4 MB
    float* winv      = (float*)((char*)d_ws + (size_t)N_CHILD * 128);      // 256 KB
    float* wfold     = (float*)((char*)winv + (size_t)N_CHILD * 4);        // 4 MB
    int*   row_start = (int*)((char*)wfold + (size_t)NNZ_TOTAL * 4);       // 128 KB

    exp_transpose_fp8_kernel<<<N_CHILD / 64, 256, 0, stream>>>(child_ll, ex8, winv);
    prep_kernel<<<1024 + 129, 256, 0, stream>>>(log_w, cols, winv, rows,
                                                wfold, row_start);
    sum_rows_kernel<<<N_NODES / 4, 256, 0, stream>>>(ex8, wfold, log_w, cols,
                                                     row_start, out);
}